// Round 8
// baseline (11776.981 us; speedup 1.0000x reference)
//
#include <hip/hip_runtime.h>
#include <hip/hip_cooperative_groups.h>

namespace cg = cooperative_groups;

typedef unsigned short u16;
typedef __attribute__((ext_vector_type(8))) short short8;
typedef __attribute__((ext_vector_type(4))) float f32x4;

#define T_ 256
#define B_ 32
#define F_ 512
#define H_ 1024
#define O_ 512
#define KT 1536    // H + F
#define NC 4096    // 4 gates * H, interleaved c = n*4 + g
#define G_ 64      // recurrence workgroups

// ---------------- ws byte offsets ----------------
#define WT_OFF  0                                     // Wt  bf16 [4096][1536]
#define XB_OFF  (WT_OFF + (size_t)NC * KT * 2)        // xb  bf16 [256][64][512]
#define FCO_OFF (XB_OFF + (size_t)256 * 64 * 512 * 2) // fcoT bf16 [512][2048]
#define BS_OFF  (FCO_OFF + (size_t)512 * 2048 * 2)    // bsum f32 [4096] interleaved
#define H0_OFF  (BS_OFF + (size_t)NC * 4)             // h0  bf16 [64][1024] zeros
#define HS_OFF  (H0_OFF + (size_t)64 * H_ * 2)        // hs  bf16 [256][64][1024]
#define BAR_OFF (HS_OFF + (size_t)256 * 64 * H_ * 2)  // barrier flags: 2048 ints
// total ~65.2 MB + 8KB

__device__ inline u16 f2bf(float f) {   // round-to-nearest-even f32 -> bf16
    unsigned u = __builtin_bit_cast(unsigned, f);
    u += 0x7FFFu + ((u >> 16) & 1u);
    return (u16)(u >> 16);
}

// Build Wt[c][k] bf16: c = n*4 + g interleaved; k<1024 h-part, else x-part
__global__ void prep_wt(const float* __restrict__ Wx, const float* __restrict__ Wh,
                        u16* __restrict__ Wt) {
    int idx = blockIdx.x * 256 + threadIdx.x;       // over 4096*1536
    int c = idx / KT;
    int k = idx - c * KT;
    int g  = c & 3;
    int n  = c >> 2;          // 0..1023
    int q  = n >> 8;
    int nn = n & 255;
    const int   comp[4][4] = {{0,1,2,3},{1,0,3,2},{2,3,0,1},{3,2,1,0}};
    const float sgn [4][4] = {{1.f,-1.f,-1.f,-1.f},
                              {1.f, 1.f,-1.f, 1.f},
                              {1.f, 1.f, 1.f,-1.f},
                              {1.f,-1.f, 1.f, 1.f}};
    float v;
    if (k < H_) {
        int p = k >> 8, kk = k & 255;
        v = sgn[q][p] * Wh[((size_t)(g * 4 + comp[q][p]) * 256 + kk) * 256 + nn];
    } else {
        int k2 = k - H_;
        int p = k2 >> 7, kk = k2 & 127;
        v = sgn[q][p] * Wx[((size_t)(g * 4 + comp[q][p]) * 128 + kk) * 256 + nn];
    }
    Wt[idx] = f2bf(v);
}

// xb16[t][bb][f]: bb<32 -> x[t][bb][f], else x[255-t][bb-32][f]
__global__ void prep_xb(const float* __restrict__ x, u16* __restrict__ xb) {
    int idx = blockIdx.x * 256 + threadIdx.x;       // over 256*64*512
    int f  = idx & (F_ - 1);
    int r  = idx >> 9;
    int bb = r & 63;
    int t  = r >> 6;
    float v = (bb < B_) ? x[((size_t)t * B_ + bb) * F_ + f]
                        : x[((size_t)(T_ - 1 - t) * B_ + (bb - B_)) * F_ + f];
    xb[idx] = f2bf(v);
}

// fcoT[o][k] = fco_w[k][o]
__global__ void prep_fco(const float* __restrict__ fco_w, u16* __restrict__ fcoT) {
    int idx = blockIdx.x * 256 + threadIdx.x;       // over 512*2048
    int k = idx & 2047;
    int o = idx >> 11;
    fcoT[idx] = f2bf(fco_w[(size_t)k * O_ + o]);
}

// bsum interleaved + h0 zeros + barrier flags zeroed
__global__ void prep_bs(const float* __restrict__ bx, const float* __restrict__ bh,
                        float* __restrict__ bs, unsigned* __restrict__ h0w,
                        int* __restrict__ bar) {
    int idx = blockIdx.x * 256 + threadIdx.x;
    if (idx < NC) {
        int n = idx >> 2, g = idx & 3;
        bs[idx] = bx[g * H_ + n] + bh[g * H_ + n];
    }
    if (idx < 64 * H_ / 2) h0w[idx] = 0u;           // bf16 zeros for h0
    if (idx < 2048)        bar[idx] = 0;            // arrive flags + gen
}

// swizzled LDS address for Wl (col-major rows of 2048B, XOR bits 4-6 by col&7)
#define WL_ADDR(col, kbyte) (((col) << 11) + ((kbyte) ^ (((col) & 7) << 4)))

// ---------------------------------------------------------------------------
// Flag-array grid barrier: one release store per wg (own cacheline), wg0 wave0
// gathers 64 flags (1 lane each), publishes gen; all waves acquire-poll gen.
// ---------------------------------------------------------------------------
__device__ __forceinline__ void flag_barrier(int* bar, int wg, int tid, int target) {
    __syncthreads();                    // all wg stores (h) issued before release
    if (tid == 0)
        __hip_atomic_store(&bar[wg * 16], target, __ATOMIC_RELEASE, __HIP_MEMORY_SCOPE_AGENT);
    int* genp = &bar[G_ * 16];
    if (wg == 0) {
        if (tid < 64) {                 // wave 0: lane l polls wg l's flag
            while (__hip_atomic_load(&bar[tid * 16], __ATOMIC_ACQUIRE,
                                     __HIP_MEMORY_SCOPE_AGENT) < target) {}
        }
        __syncthreads();
        if (tid == 0)
            __hip_atomic_store(genp, target, __ATOMIC_RELEASE, __HIP_MEMORY_SCOPE_AGENT);
    } else {
        if ((tid & 63) == 0) {          // one lane per wave acquires
            while (__hip_atomic_load(genp, __ATOMIC_ACQUIRE,
                                     __HIP_MEMORY_SCOPE_AGENT) < target) {}
        }
        __syncthreads();
    }
}

// ---------------------------------------------------------------------------
// Recurrence: 64 wgs x 1024 threads (16 waves, 4m x 4n). wg owns 64 interleaved
// cols (16 hidden units x 4 gates), full K=1536. Wh-slice (128KB) in LDS
// (XOR-swizzled); A (h,x) + Wx-slice direct from global/L2. Custom barrier.
// ---------------------------------------------------------------------------
__global__ __launch_bounds__(1024) void recur(
    const u16* __restrict__ Wt, const u16* __restrict__ xb,
    const float* __restrict__ bs, const u16* __restrict__ h0,
    u16* __restrict__ hs, int* __restrict__ bar) {
    __shared__ __align__(16) u16  Wl[G_ * 1024];     // 128KB swizzled Wh slice
    __shared__ float Cwm[64][68];                    // 17.4KB C exchange
    __shared__ u16  Hl[64][16];                      // 2KB h staging

    const int tid = threadIdx.x;
    const int wg  = blockIdx.x;
    const int l   = tid & 63;
    const int w   = tid >> 6;
    const int mw  = w & 3;          // m-tile: rows mw*16..+16
    const int nw  = w >> 2;         // n-tile: cols nw*16..+16
    const int lr  = l & 15;
    const int lq  = l >> 4;
    const int c0c = wg * 64;        // first interleaved col of this wg
    const int colw = nw * 16 + lr;  // B col within wg tile (0..63)

    // ---- preload Wh slice into LDS (swizzled), 8 x 16B per thread ----
    for (int i = 0; i < 8; ++i) {
        int id  = tid + (i << 10);          // 0..8191 chunks of 8 elems
        int col = id >> 7;                  // 0..63
        int kc  = id & 127;                 // k chunk (8 elems)
        short8 v = *(const short8*)(Wt + (size_t)(c0c + col) * KT + kc * 8);
        *(short8*)((char*)Wl + WL_ADDR(col, kc * 16)) = v;
    }

    // gate-math mapping: thread -> (row, j): row = tid>>4, j = tid&15
    const int grow = tid >> 4;
    const int gj   = tid & 15;
    const f32x4 bsv = *(const f32x4*)(bs + c0c + gj * 4);

    const u16* bxp = Wt + (size_t)(c0c + colw) * KT + H_ + lq * 8;  // Wx B-frags
    float cst = 0.f;
    const u16* hprev = h0;
    __syncthreads();                 // Wl ready

    for (int t = 0; t < T_; ++t) {
        const u16* hrow = hprev + (size_t)(mw * 16 + lr) * H_ + lq * 8;
        const u16* xrow = xb + ((size_t)t * 64 + mw * 16 + lr) * F_ + lq * 8;
        f32x4 acc = {0.f, 0.f, 0.f, 0.f};
        #pragma unroll 4
        for (int kk = 0; kk < 32; ++kk) {       // h-part K=1024, B from LDS
            short8 a = *(const short8*)(hrow + kk * 32);
            short8 b = *(const short8*)((const char*)Wl +
                        WL_ADDR(colw, kk * 64 + lq * 16));
            acc = __builtin_amdgcn_mfma_f32_16x16x32_bf16(a, b, acc, 0, 0, 0);
        }
        #pragma unroll 4
        for (int kk = 0; kk < 16; ++kk) {       // x-part K=512, B from global
            short8 a = *(const short8*)(xrow + kk * 32);
            short8 b = *(const short8*)(bxp + kk * 32);
            acc = __builtin_amdgcn_mfma_f32_16x16x32_bf16(a, b, acc, 0, 0, 0);
        }
        // C layout: col = l&15, row = (l>>4)*4 + r
        #pragma unroll
        for (int r = 0; r < 4; ++r) Cwm[mw * 16 + lq * 4 + r][colw] = acc[r];
        __syncthreads();
        // gate math: one (row, hidden-unit) per thread
        {
            f32x4 cv = *(const f32x4*)(&Cwm[grow][gj * 4]);
            float pf = cv.x + bsv.x;
            float pi = cv.y + bsv.y;
            float po = cv.z + bsv.z;
            float pa = cv.w + bsv.w;
            float ft = 1.f / (1.f + expf(-pf));
            float it = 1.f / (1.f + expf(-pi));
            float ot = 1.f / (1.f + expf(-po));
            cst = it * tanhf(pa) + ft * cst;
            Hl[grow][gj] = f2bf(ot * tanhf(cst));
        }
        __syncthreads();
        if (tid < 64) {                          // 32B contiguous h write per row
            uint4* d = (uint4*)(hs + (size_t)t * (64 * H_) + (size_t)tid * H_ + wg * 16);
            const uint4* s = (const uint4*)(&Hl[tid][0]);
            d[0] = s[0]; d[1] = s[1];
        }
        flag_barrier(bar, wg, tid, t + 1);
        hprev = hs + (size_t)t * (64 * H_);
    }
}

// ---------------------------------------------------------------------------
// Final GEMM (MFMA): out[t][b][o] = [h_f | h_b] @ fco_w + fco_b
// grid (16, 256) x 256 thr; wave: m0 = (w&1)*16, c0 = bx*32 + (w>>1)*16; K=2048.
// ---------------------------------------------------------------------------
__global__ __launch_bounds__(256) void finalk(
    const u16* __restrict__ hs, const u16* __restrict__ fcoT,
    const float* __restrict__ fco_b, float* __restrict__ out) {
    const int tid = threadIdx.x;
    const int l = tid & 63, w = tid >> 6;
    const int t  = blockIdx.y;
    const int m0 = (w & 1) * 16;
    const int c0 = blockIdx.x * 32 + (w >> 1) * 16;
    const int lr = l & 15, lq = l >> 4;
    const u16* bp = fcoT + (size_t)(c0 + lr) * 2048 + lq * 8;
    const u16* af = hs + ((size_t)t * 64 + m0 + lr) * H_ + lq * 8;             // h_f
    const u16* ab = hs + ((size_t)(T_ - 1 - t) * 64 + B_ + m0 + lr) * H_ + lq * 8; // h_b
    f32x4 acc = {0.f, 0.f, 0.f, 0.f};
    for (int kk = 0; kk < 32; ++kk) {
        short8 a = *(const short8*)(af + kk * 32);
        short8 b = *(const short8*)(bp + kk * 32);
        acc = __builtin_amdgcn_mfma_f32_16x16x32_bf16(a, b, acc, 0, 0, 0);
    }
    for (int kk = 0; kk < 32; ++kk) {
        short8 a = *(const short8*)(ab + kk * 32);
        short8 b = *(const short8*)(bp + 1024 + kk * 32);
        acc = __builtin_amdgcn_mfma_f32_16x16x32_bf16(a, b, acc, 0, 0, 0);
    }
    const int col = c0 + lr;
    const float bb = fco_b[col];
    #pragma unroll
    for (int r = 0; r < 4; ++r) {
        int b = m0 + lq * 4 + r;
        out[((size_t)t * B_ + b) * O_ + col] = acc[r] + bb;
    }
}

extern "C" void kernel_launch(void* const* d_in, const int* in_sizes, int n_in,
                              void* d_out, int out_size, void* d_ws, size_t ws_size,
                              hipStream_t stream) {
    const float* x     = (const float*)d_in[0];
    const float* Wx    = (const float*)d_in[1];
    const float* bx    = (const float*)d_in[2];
    const float* Wh    = (const float*)d_in[3];
    const float* bh    = (const float*)d_in[4];
    const float* fco_w = (const float*)d_in[5];
    const float* fco_b = (const float*)d_in[6];
    float* out = (float*)d_out;
    char*  ws  = (char*)d_ws;

    u16*   Wt   = (u16*)(ws + WT_OFF);
    u16*   xb16 = (u16*)(ws + XB_OFF);
    u16*   fcoT = (u16*)(ws + FCO_OFF);
    float* bsum = (float*)(ws + BS_OFF);
    u16*   h0   = (u16*)(ws + H0_OFF);
    u16*   hs   = (u16*)(ws + HS_OFF);
    int*   bar  = (int*)(ws + BAR_OFF);

    prep_wt<<<(NC * KT) / 256, 256, 0, stream>>>(Wx, Wh, Wt);
    prep_xb<<<(T_ * 64 * F_) / 256, 256, 0, stream>>>(x, xb16);
    prep_fco<<<(O_ * 2048) / 256, 256, 0, stream>>>(fco_w, fcoT);
    prep_bs<<<(64 * H_ / 2) / 256, 256, 0, stream>>>(bx, bh, bsum, (unsigned*)h0, bar);

    void* args[] = {(void*)&Wt, (void*)&xb16, (void*)&bsum, (void*)&h0,
                    (void*)&hs, (void*)&bar};
    hipLaunchCooperativeKernel((void*)recur, dim3(G_), dim3(1024), args, 0, stream);

    finalk<<<dim3(16, T_), 256, 0, stream>>>(hs, fcoT, fco_b, out);
}

// Round 11
// 8560.969 us; speedup vs baseline: 1.3757x; 1.3757x over previous
//
#include <hip/hip_runtime.h>
#include <hip/hip_cooperative_groups.h>

namespace cg = cooperative_groups;

typedef unsigned short u16;
typedef unsigned long long u64;
typedef __attribute__((ext_vector_type(8))) short short8;
typedef __attribute__((ext_vector_type(4))) float f32x4;

#define T_ 256
#define B_ 32
#define F_ 512
#define H_ 1024
#define O_ 512
#define KT 1536    // H + F
#define NC 4096    // 4 gates * H, interleaved c = n*4 + g
#define G_ 64      // recurrence workgroups

// ---------------- ws byte offsets ----------------
#define WT_OFF  0                                     // Wt  bf16 [4096][1536]
#define XB_OFF  (WT_OFF + (size_t)NC * KT * 2)        // xb  bf16 [256][64][512]
#define FCO_OFF (XB_OFF + (size_t)256 * 64 * 512 * 2) // fcoT bf16 [512][2048]
#define BS_OFF  (FCO_OFF + (size_t)512 * 2048 * 2)    // bsum f32 [4096] interleaved
#define H0_OFF  (BS_OFF + (size_t)NC * 4)             // h0  bf16 [64][1024] zeros
#define HS_OFF  (H0_OFF + (size_t)64 * H_ * 2)        // hs  bf16 [256][64][1024]
#define BAR_OFF (HS_OFF + (size_t)256 * 64 * H_ * 2)  // barrier flags: 2048 ints
// total ~65.2 MB + 8KB

__device__ inline u16 f2bf(float f) {   // round-to-nearest-even f32 -> bf16
    unsigned u = __builtin_bit_cast(unsigned, f);
    u += 0x7FFFu + ((u >> 16) & 1u);
    return (u16)(u >> 16);
}

// Build Wt[c][k] bf16: c = n*4 + g interleaved; k<1024 h-part, else x-part
__global__ void prep_wt(const float* __restrict__ Wx, const float* __restrict__ Wh,
                        u16* __restrict__ Wt) {
    int idx = blockIdx.x * 256 + threadIdx.x;       // over 4096*1536
    int c = idx / KT;
    int k = idx - c * KT;
    int g  = c & 3;
    int n  = c >> 2;          // 0..1023
    int q  = n >> 8;
    int nn = n & 255;
    const int   comp[4][4] = {{0,1,2,3},{1,0,3,2},{2,3,0,1},{3,2,1,0}};
    const float sgn [4][4] = {{1.f,-1.f,-1.f,-1.f},
                              {1.f, 1.f,-1.f, 1.f},
                              {1.f, 1.f, 1.f,-1.f},
                              {1.f,-1.f, 1.f, 1.f}};
    float v;
    if (k < H_) {
        int p = k >> 8, kk = k & 255;
        v = sgn[q][p] * Wh[((size_t)(g * 4 + comp[q][p]) * 256 + kk) * 256 + nn];
    } else {
        int k2 = k - H_;
        int p = k2 >> 7, kk = k2 & 127;
        v = sgn[q][p] * Wx[((size_t)(g * 4 + comp[q][p]) * 128 + kk) * 256 + nn];
    }
    Wt[idx] = f2bf(v);
}

// xb16[t][bb][f]: bb<32 -> x[t][bb][f], else x[255-t][bb-32][f]
__global__ void prep_xb(const float* __restrict__ x, u16* __restrict__ xb) {
    int idx = blockIdx.x * 256 + threadIdx.x;       // over 256*64*512
    int f  = idx & (F_ - 1);
    int r  = idx >> 9;
    int bb = r & 63;
    int t  = r >> 6;
    float v = (bb < B_) ? x[((size_t)t * B_ + bb) * F_ + f]
                        : x[((size_t)(T_ - 1 - t) * B_ + (bb - B_)) * F_ + f];
    xb[idx] = f2bf(v);
}

// fcoT[o][k] = fco_w[k][o]
__global__ void prep_fco(const float* __restrict__ fco_w, u16* __restrict__ fcoT) {
    int idx = blockIdx.x * 256 + threadIdx.x;       // over 512*2048
    int k = idx & 2047;
    int o = idx >> 11;
    fcoT[idx] = f2bf(fco_w[(size_t)k * O_ + o]);
}

// bsum interleaved + h0 zeros + barrier flags zeroed
__global__ void prep_bs(const float* __restrict__ bx, const float* __restrict__ bh,
                        float* __restrict__ bs, unsigned* __restrict__ h0w,
                        int* __restrict__ bar) {
    int idx = blockIdx.x * 256 + threadIdx.x;
    if (idx < NC) {
        int n = idx >> 2, g = idx & 3;
        bs[idx] = bx[g * H_ + n] + bh[g * H_ + n];
    }
    if (idx < 64 * H_ / 2) h0w[idx] = 0u;           // bf16 zeros for h0
    if (idx < 2048)        bar[idx] = 0;            // arrive flags
}

// swizzled LDS address for Wl (col-major rows of 2048B, XOR bits 4-6 by col&7)
#define WL_ADDR(col, kbyte) (((col) << 11) + ((kbyte) ^ (((col) & 7) << 4)))

// ---------------------------------------------------------------------------
// Recurrence: 64 wgs x 1024 threads (16 waves, 4m x 4n). wg owns 64 interleaved
// cols, full K=1536. Wh-slice (128KB) LDS-resident (swizzled). h exchange:
// producer stores via RELAXED agent atomics (sc0 sc1 -> L3, no wbl2), orders
// with explicit vmcnt(0), then relaxed flag store. Consumers poll flags with
// RELAXED agent loads (no buffer_inv!) and read h with PLAIN cached loads --
// hs[t] addresses are virgin per step, so first touch fetches fresh L3 data.
// No cache-maintenance instruction anywhere in the 256-step loop.
// ---------------------------------------------------------------------------
__global__ __launch_bounds__(1024) void recur(
    const u16* __restrict__ Wt, const u16* __restrict__ xb,
    const float* __restrict__ bs, const u16* __restrict__ h0,
    u16* __restrict__ hs, int* __restrict__ bar) {
    __shared__ __align__(16) u16  Wl[G_ * 1024];     // 128KB swizzled Wh slice
    __shared__ float Cwm[64][68];                    // 17.4KB C exchange
    __shared__ u16  Hl[64][16];                      // 2KB h staging

    const int tid = threadIdx.x;
    const int wg  = blockIdx.x;
    const int l   = tid & 63;
    const int w   = tid >> 6;
    const int mw  = w & 3;          // m-tile: rows mw*16..+16
    const int nw  = w >> 2;         // n-tile: cols nw*16..+16
    const int lr  = l & 15;
    const int lq  = l >> 4;
    const int c0c = wg * 64;        // first interleaved col of this wg
    const int colw = nw * 16 + lr;  // B col within wg tile (0..63)

    // ---- preload Wh slice into LDS (swizzled), 8 x 16B per thread ----
    for (int i = 0; i < 8; ++i) {
        int id  = tid + (i << 10);          // 0..8191 chunks of 8 elems
        int col = id >> 7;                  // 0..63
        int kc  = id & 127;                 // k chunk (8 elems)
        short8 v = *(const short8*)(Wt + (size_t)(c0c + col) * KT + kc * 8);
        *(short8*)((char*)Wl + WL_ADDR(col, kc * 16)) = v;
    }

    // gate-math mapping: thread -> (row, j): row = tid>>4, j = tid&15
    const int grow = tid >> 4;
    const int gj   = tid & 15;
    const f32x4 bsv = *(const f32x4*)(bs + c0c + gj * 4);

    const u16* bxp = Wt + (size_t)(c0c + colw) * KT + H_ + lq * 8;  // Wx B-frags
    float cst = 0.f;
    const u16* hprev = h0;
    __syncthreads();                 // Wl ready

    #pragma unroll 1
    for (int t = 0; t < T_; ++t) {
        const u16* hrow = hprev + (size_t)(mw * 16 + lr) * H_ + lq * 8;
        const u16* xrow = xb + ((size_t)t * 64 + mw * 16 + lr) * F_ + lq * 8;
        f32x4 acc = {0.f, 0.f, 0.f, 0.f};
        #pragma unroll 4
        for (int kk = 0; kk < 32; ++kk) {       // h-part K=1024: A cached, B LDS
            short8 a = *(const short8*)(hrow + kk * 32);
            short8 b = *(const short8*)((const char*)Wl +
                        WL_ADDR(colw, kk * 64 + lq * 16));
            acc = __builtin_amdgcn_mfma_f32_16x16x32_bf16(a, b, acc, 0, 0, 0);
        }
        #pragma unroll 4
        for (int kk = 0; kk < 16; ++kk) {       // x-part K=512: both cached
            short8 a = *(const short8*)(xrow + kk * 32);
            short8 b = *(const short8*)(bxp + kk * 32);
            acc = __builtin_amdgcn_mfma_f32_16x16x32_bf16(a, b, acc, 0, 0, 0);
        }
        // C layout: col = l&15, row = (l>>4)*4 + r
        #pragma unroll
        for (int r = 0; r < 4; ++r) Cwm[mw * 16 + lq * 4 + r][colw] = acc[r];
        __syncthreads();
        // gate math: one (row, hidden-unit) per thread
        {
            f32x4 cv = *(const f32x4*)(&Cwm[grow][gj * 4]);
            float pf = cv.x + bsv.x;
            float pi = cv.y + bsv.y;
            float po = cv.z + bsv.z;
            float pa = cv.w + bsv.w;
            float ft = 1.f / (1.f + expf(-pf));
            float it = 1.f / (1.f + expf(-pi));
            float ot = 1.f / (1.f + expf(-po));
            cst = it * tanhf(pa) + ft * cst;
            Hl[grow][gj] = f2bf(ot * tanhf(cst));
        }
        __syncthreads();             // Hl ready + Cwm WAR protection
        u16* hst = hs + (size_t)t * (64 * H_);
        if (tid < 64) {              // wave 0: bypass-store h row, then flag
            const u64* s = (const u64*)(&Hl[tid][0]);
            u64* d = (u64*)(hst + (size_t)tid * H_ + wg * 16);
            __hip_atomic_store(&d[0], s[0], __ATOMIC_RELAXED, __HIP_MEMORY_SCOPE_AGENT);
            __hip_atomic_store(&d[1], s[1], __ATOMIC_RELAXED, __HIP_MEMORY_SCOPE_AGENT);
            __hip_atomic_store(&d[2], s[2], __ATOMIC_RELAXED, __HIP_MEMORY_SCOPE_AGENT);
            __hip_atomic_store(&d[3], s[3], __ATOMIC_RELAXED, __HIP_MEMORY_SCOPE_AGENT);
            asm volatile("s_waitcnt vmcnt(0)" ::: "memory");   // h at L3
            if (tid == 0)
                __hip_atomic_store(&bar[wg * 16], t + 1,
                                   __ATOMIC_RELAXED, __HIP_MEMORY_SCOPE_AGENT);
        }
        // flat barrier: every wave's lane l polls wg l's flag (relaxed, no inv)
        {
            int fv;
            do {
                fv = __hip_atomic_load(&bar[l * 16],
                                       __ATOMIC_RELAXED, __HIP_MEMORY_SCOPE_AGENT);
            } while (__ballot(fv < t + 1));
        }
        asm volatile("" ::: "memory");           // no load hoisting above poll
        __builtin_amdgcn_sched_barrier(0);
        hprev = hst;
    }
}

// ---------------------------------------------------------------------------
// Final GEMM (MFMA): out[t][b][o] = [h_f | h_b] @ fco_w + fco_b
// grid (16, 256) x 256 thr; wave: m0 = (w&1)*16, c0 = bx*32 + (w>>1)*16; K=2048.
// ---------------------------------------------------------------------------
__global__ __launch_bounds__(256) void finalk(
    const u16* __restrict__ hs, const u16* __restrict__ fcoT,
    const float* __restrict__ fco_b, float* __restrict__ out) {
    const int tid = threadIdx.x;
    const int l = tid & 63, w = tid >> 6;
    const int t  = blockIdx.y;
    const int m0 = (w & 1) * 16;
    const int c0 = blockIdx.x * 32 + (w >> 1) * 16;
    const int lr = l & 15, lq = l >> 4;
    const u16* bp = fcoT + (size_t)(c0 + lr) * 2048 + lq * 8;
    const u16* af = hs + ((size_t)t * 64 + m0 + lr) * H_ + lq * 8;             // h_f
    const u16* ab = hs + ((size_t)(T_ - 1 - t) * 64 + B_ + m0 + lr) * H_ + lq * 8; // h_b
    f32x4 acc = {0.f, 0.f, 0.f, 0.f};
    for (int kk = 0; kk < 32; ++kk) {
        short8 a = *(const short8*)(af + kk * 32);
        short8 b = *(const short8*)(bp + kk * 32);
        acc = __builtin_amdgcn_mfma_f32_16x16x32_bf16(a, b, acc, 0, 0, 0);
    }
    for (int kk = 0; kk < 32; ++kk) {
        short8 a = *(const short8*)(ab + kk * 32);
        short8 b = *(const short8*)(bp + 1024 + kk * 32);
        acc = __builtin_amdgcn_mfma_f32_16x16x32_bf16(a, b, acc, 0, 0, 0);
    }
    const int col = c0 + lr;
    const float bb = fco_b[col];
    #pragma unroll
    for (int r = 0; r < 4; ++r) {
        int b = m0 + lq * 4 + r;
        out[((size_t)t * B_ + b) * O_ + col] = acc[r] + bb;
    }
}

extern "C" void kernel_launch(void* const* d_in, const int* in_sizes, int n_in,
                              void* d_out, int out_size, void* d_ws, size_t ws_size,
                              hipStream_t stream) {
    const float* x     = (const float*)d_in[0];
    const float* Wx    = (const float*)d_in[1];
    const float* bx    = (const float*)d_in[2];
    const float* Wh    = (const float*)d_in[3];
    const float* bh    = (const float*)d_in[4];
    const float* fco_w = (const float*)d_in[5];
    const float* fco_b = (const float*)d_in[6];
    float* out = (float*)d_out;
    char*  ws  = (char*)d_ws;

    u16*   Wt   = (u16*)(ws + WT_OFF);
    u16*   xb16 = (u16*)(ws + XB_OFF);
    u16*   fcoT = (u16*)(ws + FCO_OFF);
    float* bsum = (float*)(ws + BS_OFF);
    u16*   h0   = (u16*)(ws + H0_OFF);
    u16*   hs   = (u16*)(ws + HS_OFF);
    int*   bar  = (int*)(ws + BAR_OFF);

    prep_wt<<<(NC * KT) / 256, 256, 0, stream>>>(Wx, Wh, Wt);
    prep_xb<<<(T_ * 64 * F_) / 256, 256, 0, stream>>>(x, xb16);
    prep_fco<<<(O_ * 2048) / 256, 256, 0, stream>>>(fco_w, fcoT);
    prep_bs<<<(64 * H_ / 2) / 256, 256, 0, stream>>>(bx, bh, bsum, (unsigned*)h0, bar);

    void* args[] = {(void*)&Wt, (void*)&xb16, (void*)&bsum, (void*)&h0,
                    (void*)&hs, (void*)&bar};
    (void)hipLaunchCooperativeKernel((void*)recur, dim3(G_), dim3(1024), args, 0, stream);

    finalk<<<dim3(16, T_), 256, 0, stream>>>(hs, fcoT, fco_b, out);
}